// Round 1
// baseline (7010.094 us; speedup 1.0000x reference)
//
#include <hip/hip_runtime.h>
#include <cmath>

typedef unsigned int u32;
typedef unsigned long long u64;

#define TCAND 4768
#define RTOT  261888
#define NW    75
#define NROWS 4800
#define NEGV  -1e9f

__device__ __forceinline__ u32 fkey(float s){
  u32 u = __float_as_uint(s);
  return u ^ ((u >> 31) ? 0xFFFFFFFFu : 0x80000000u);
}

// -------- descending bitonic sort of u64 in LDS (N power of two) --------
__device__ void bitonic_desc(u64* a, int N, int t, int nt){
  for (int len = 2; len <= N; len <<= 1){
    for (int inc = len >> 1; inc > 0; inc >>= 1){
      __syncthreads();
      for (int idx = t; idx < (N >> 1); idx += nt){
        int i = 2*idx - (idx & (inc - 1));
        int j = i + inc;
        u64 x = a[i], y = a[j];
        bool descR = ((i & len) == 0);
        bool sw = descR ? (x < y) : (x > y);
        if (sw){ a[i] = y; a[j] = x; }
      }
    }
  }
  __syncthreads();
}

// -------- kernel 0: transpose w_inter [oc][ic*9] -> w_r [ic*9][oc] --------
__global__ void wtrans(const float* __restrict__ w, float* __restrict__ w_r){
  int i = blockIdx.x * 256 + threadIdx.x;
  if (i >= 589824) return;               // 256*2304
  int oc = i / 2304; int r = i - oc * 2304;
  w_r[r * 256 + oc] = w[i];
}

// -------- kernel 1: fused conv3x3+ReLU -> 1x1 heads -> decode -> per-level buffers --------
__global__ __launch_bounds__(256) void conv_fused(
    const float* __restrict__ feat, const float* __restrict__ w_r,
    const float* __restrict__ b_inter, const float* __restrict__ w_logits,
    const float* __restrict__ b_logits, const float* __restrict__ w_reg,
    const float* __restrict__ b_reg, const int* __restrict__ imgp,
    float* __restrict__ score_base, float* __restrict__ box_base,
    int H, int W, int stridev, int asize, int foff)
{
  __shared__ float lds_w[36 * 320];   // 4 ic * 9 taps, [row][16 tx][20 pad]
  __shared__ float lds_x[4 * 110];    // 4 ic, [10][11]
  __shared__ float outb[15 * 64];

  const int t = threadIdx.x;
  const int tilesW = W >> 3;
  const int tile = blockIdx.x;
  const int x0 = (tile % tilesW) << 3;
  const int y0 = (tile / tilesW) << 3;
  const int bimg = blockIdx.y;
  const int tx = t & 15, ty = t >> 4;

  float acc[64];
  #pragma unroll
  for (int i = 0; i < 64; i++) acc[i] = 0.f;

  const int r0 = ty >> 1;
  const int c0 = (ty & 1) << 2;
  const size_t featbase = (size_t)bimg * 256 * H * W;

  for (int ci = 0; ci < 64; ++ci){
    __syncthreads();
    // stage weights: 36 rows x 256 oc = 9216 floats (coalesced from w_r)
    const float4* wsrc = (const float4*)(w_r + ci * 9216);
    #pragma unroll
    for (int kk = 0; kk < 9; kk++){
      int f4 = t + (kk << 8);
      float4 v = wsrc[f4];
      int g = f4 << 2; int row = g >> 8; int oc = g & 255;
      *(float4*)&lds_w[row * 320 + (oc >> 4) * 20 + (oc & 15)] = v;
    }
    // stage input patch: 4 ic x 10x10 (zero-padded halo)
    for (int k = t; k < 400; k += 256){
      int icl = k / 100; int rem = k - icl * 100; int rr = rem / 10; int cc = rem - rr * 10;
      int gy = y0 - 1 + rr, gx = x0 - 1 + cc;
      int ic = (ci << 2) + icl;
      float v = 0.f;
      if (gy >= 0 && gy < H && gx >= 0 && gx < W)
        v = feat[featbase + ((size_t)ic * H + gy) * W + gx];
      lds_x[icl * 110 + rr * 11 + cc] = v;
    }
    __syncthreads();
    #pragma unroll
    for (int icl = 0; icl < 4; ++icl){
      #pragma unroll
      for (int ky = 0; ky < 3; ++ky){
        #pragma unroll
        for (int kx = 0; kx < 3; ++kx){
          float wv[16];
          const int wb = (icl * 9 + ky * 3 + kx) * 320 + tx * 20;
          *(float4*)&wv[0]  = *(const float4*)&lds_w[wb];
          *(float4*)&wv[4]  = *(const float4*)&lds_w[wb + 4];
          *(float4*)&wv[8]  = *(const float4*)&lds_w[wb + 8];
          *(float4*)&wv[12] = *(const float4*)&lds_w[wb + 12];
          float xv[4];
          const int xb = icl * 110 + (r0 + ky) * 11 + (c0 + kx);
          #pragma unroll
          for (int pp = 0; pp < 4; pp++) xv[pp] = lds_x[xb + pp];
          #pragma unroll
          for (int o = 0; o < 16; o++){
            #pragma unroll
            for (int pp = 0; pp < 4; pp++)
              acc[(o << 2) + pp] = __builtin_fmaf(wv[o], xv[pp], acc[(o << 2) + pp]);
          }
        }
      }
    }
  }
  __syncthreads();
  // epilogue: bias+relu then 1x1 heads (15 outputs), partial per tx then shfl-reduce
  float po[60];
  #pragma unroll
  for (int i = 0; i < 60; i++) po[i] = 0.f;
  #pragma unroll
  for (int o16 = 0; o16 < 16; o16++){
    int oc = (tx << 4) + o16;
    float bb = b_inter[oc];
    float v[4];
    #pragma unroll
    for (int pp = 0; pp < 4; pp++) v[pp] = fmaxf(acc[(o16 << 2) + pp] + bb, 0.f);
    #pragma unroll
    for (int o = 0; o < 15; o++){
      float wv = (o < 3) ? w_logits[o * 256 + oc] : w_reg[(o - 3) * 256 + oc];
      #pragma unroll
      for (int pp = 0; pp < 4; pp++) po[o * 4 + pp] = __builtin_fmaf(wv, v[pp], po[o * 4 + pp]);
    }
  }
  #pragma unroll
  for (int m = 1; m < 16; m <<= 1){
    #pragma unroll
    for (int j = 0; j < 60; j++) po[j] += __shfl_xor(po[j], m, 16);
  }
  if (tx == 0){
    int pxb = ty << 2;
    #pragma unroll
    for (int o = 0; o < 15; o++){
      #pragma unroll
      for (int pp = 0; pp < 4; pp++) outb[(o << 6) + pxb + pp] = po[o * 4 + pp];
    }
  }
  __syncthreads();
  if (t < 192){
    int a = t >> 6; int px = t & 63;
    int r = px >> 3, c = px & 7;
    int y = y0 + r, x = x0 + c;
    float img = (float)(*imgp);
    float sc = outb[(a << 6) + px] + b_logits[a];
    float d0 = outb[((3 + a * 4 + 0) << 6) + px] + b_reg[a * 4 + 0];
    float d1 = outb[((3 + a * 4 + 1) << 6) + px] + b_reg[a * 4 + 1];
    float d2 = outb[((3 + a * 4 + 2) << 6) + px] + b_reg[a * 4 + 2];
    float d3 = outb[((3 + a * 4 + 3) << 6) + px] + b_reg[a * 4 + 3];
    // anchor base in double (matches numpy)
    double ar = (a == 0) ? 0.5 : ((a == 1) ? 1.0 : 2.0);
    double area_d = (double)asize * (double)asize;
    double wd = sqrt(area_d / ar);
    double hd = ar * wd;
    float bx1 = (float)(-wd * 0.5), by1 = (float)(-hd * 0.5);
    float bx2 = (float)( wd * 0.5), by2 = (float)( hd * 0.5);
    float sx = (float)(x * stridev), sy = (float)(y * stridev);
    float ax1 = sx + bx1, ay1 = sy + by1, ax2 = sx + bx2, ay2 = sy + by2;
    float aw = __fsub_rn(ax2, ax1), ah = __fsub_rn(ay2, ay1);
    float acx = __fadd_rn(ax1, __fmul_rn(0.5f, aw));
    float acy = __fadd_rn(ay1, __fmul_rn(0.5f, ah));
    const float CLAMP = (float)4.135166556742356;
    float dwv = fminf(d2, CLAMP), dhv = fminf(d3, CLAMP);
    float pcx = __fadd_rn(__fmul_rn(d0, aw), acx);
    float pcy = __fadd_rn(__fmul_rn(d1, ah), acy);
    float pw = __fmul_rn((float)exp((double)dwv), aw);
    float ph = __fmul_rn((float)exp((double)dhv), ah);
    float hx = __fmul_rn(0.5f, pw), hy = __fmul_rn(0.5f, ph);
    float X1 = __fsub_rn(pcx, hx), Y1 = __fsub_rn(pcy, hy);
    float X2 = __fadd_rn(pcx, hx), Y2 = __fadd_rn(pcy, hy);
    X1 = fminf(fmaxf(X1, 0.f), img); Y1 = fminf(fmaxf(Y1, 0.f), img);
    X2 = fminf(fmaxf(X2, 0.f), img); Y2 = fminf(fmaxf(Y2, 0.f), img);
    int gi = (y * W + x) * 3 + a;
    size_t oidx = (size_t)bimg * RTOT + foff + gi;
    score_base[oidx] = sc;
    ((float4*)box_base)[oidx] = make_float4(X1, Y1, X2, Y2);
  }
}

// -------- kernel 2: per (level,image) exact top-k (radix select + bitonic) --------
__global__ __launch_bounds__(1024) void topk_lvl(
    const float* __restrict__ score_base, const float* __restrict__ box_base,
    float* __restrict__ cs, float* __restrict__ cb, int* __restrict__ clvl)
{
  const int lvl = blockIdx.x, b = blockIdx.y;
  const int Rtab[5] = {196608, 49152, 12288, 3072, 768};
  const int Ktab[5] = {1000, 1000, 1000, 1000, 768};
  const int Ftab[5] = {0, 196608, 245760, 258048, 261120};
  const int Ctab[5] = {0, 1000, 2000, 3000, 4000};
  const int R = Rtab[lvl], kk = Ktab[lvl], foff = Ftab[lvl], coff = Ctab[lvl];
  const float* sc = score_base + (size_t)b * RTOT + foff;
  const int t = threadIdx.x;
  __shared__ u32 hist[256];
  __shared__ u32 sh_prefix, sh_r;
  __shared__ u32 cgt, ceq;
  __shared__ u64 sel[1024];
  __shared__ u64 eqb[1024];
  if (t == 0){ sh_prefix = 0u; sh_r = (u32)kk; }
  __syncthreads();
  for (int pass = 0; pass < 4; ++pass){
    if (t < 256) hist[t] = 0u;
    __syncthreads();
    u32 prefix = sh_prefix;
    int shift = 24 - 8 * pass;
    u32 maskHi = (pass == 0) ? 0u : (0xFFFFFFFFu << (shift + 8));
    for (int i = t; i < R; i += 1024){
      u32 key = fkey(sc[i]);
      if ((key & maskHi) == prefix) atomicAdd(&hist[(key >> shift) & 255u], 1u);
    }
    __syncthreads();
    if (t == 0){
      u32 r = sh_r; u32 run = 0; int chosen = 255;
      for (int bv = 255; bv >= 0; --bv){
        u32 c = hist[bv];
        if (run + c >= r){ chosen = bv; break; }
        run += c;
      }
      sh_prefix = prefix | ((u32)chosen << shift);
      sh_r = r - run;
    }
    __syncthreads();
  }
  const u32 Tkey = sh_prefix; const u32 need_eq = sh_r;
  if (t == 0){ cgt = 0u; ceq = 0u; }
  __syncthreads();
  for (int i = t; i < R; i += 1024){
    u32 key = fkey(sc[i]);
    if (key > Tkey){
      u32 p = atomicAdd(&cgt, 1u);
      sel[p] = (((u64)key) << 32) | (u64)(0xFFFFFFFFu - (u32)i);
    } else if (key == Tkey){
      u32 e = atomicAdd(&ceq, 1u);
      if (e < 1024u) eqb[e] = (u64)(0xFFFFFFFFu - (u32)i);
    }
  }
  __syncthreads();
  u32 nGt = cgt; u32 nEq = ceq > 1024u ? 1024u : ceq;
  if ((u32)t >= nEq) eqb[t] = 0ull;
  __syncthreads();
  bitonic_desc(eqb, 1024, t, 1024);          // larger (0xFFFFFFFF-i) first = smaller i first
  if ((u32)t < need_eq) sel[nGt + t] = (((u64)Tkey) << 32) | (eqb[t] & 0xFFFFFFFFull);
  if (t >= kk) sel[t] = 0ull;
  __syncthreads();
  bitonic_desc(sel, 1024, t, 1024);
  if (t < kk){
    u64 v = sel[t];
    u32 i = 0xFFFFFFFFu - (u32)(v & 0xFFFFFFFFull);
    int dst = b * TCAND + coff + t;
    cs[dst] = sc[i];
    ((float4*)cb)[dst] = ((const float4*)box_base)[(size_t)b * RTOT + foff + i];
    clvl[dst] = lvl;
  }
}

// -------- kernel 3: per-image global stable sort + NMS prep --------
__global__ __launch_bounds__(1024) void gsort(
    const float* __restrict__ cs, const float* __restrict__ cb, const int* __restrict__ clvl,
    const int* __restrict__ imgp,
    float* __restrict__ s_score, float* __restrict__ s_box, float* __restrict__ obox,
    float* __restrict__ area, int* __restrict__ validarr)
{
  const int b = blockIdx.x, t = threadIdx.x;
  __shared__ u64 arr[8192];
  for (int i = t; i < 8192; i += 1024){
    u64 v = 0ull;
    if (i < TCAND){
      u32 key = fkey(cs[b * TCAND + i]);
      v = (((u64)key) << 32) | (u64)(0xFFFFFFFFu - (u32)i);
    }
    arr[i] = v;
  }
  __syncthreads();
  bitonic_desc(arr, 8192, t, 1024);
  const float img = (float)(*imgp);
  const float off1 = img + 1.0f;
  for (int s = t; s < TCAND; s += 1024){
    u32 ci = 0xFFFFFFFFu - (u32)(arr[s] & 0xFFFFFFFFull);
    int src = b * TCAND + (int)ci;
    int dst = b * TCAND + s;
    float scv = cs[src];
    float4 bx = ((const float4*)cb)[src];
    s_score[dst] = scv;
    ((float4*)s_box)[dst] = bx;
    float lv = (float)clvl[src];
    float tt = __fmul_rn(lv, off1);
    float o0 = __fadd_rn(bx.x, tt), o1 = __fadd_rn(bx.y, tt);
    float o2 = __fadd_rn(bx.z, tt), o3 = __fadd_rn(bx.w, tt);
    ((float4*)obox)[dst] = make_float4(o0, o1, o2, o3);
    area[dst] = __fmul_rn(__fsub_rn(o2, o0), __fsub_rn(o3, o1));
    validarr[dst] = (bx.z > bx.x && bx.w > bx.y) ? 1 : 0;
  }
}

// -------- kernel 4: suppression bit-matrix (j>i, IoU>0.7) --------
__global__ void iou_mat(const float* __restrict__ obox, const float* __restrict__ area,
                        u64* __restrict__ supp)
{
  const int b = blockIdx.y;
  int wid = blockIdx.x * 256 + threadIdx.x;
  const int total = TCAND * NW;
  if (wid >= total) return;
  int i = wid / NW, w = wid - i * NW;
  float4 bi = ((const float4*)obox)[b * TCAND + i];
  float ai = area[b * TCAND + i];
  u64 bits = 0ull;
  int jbase = w << 6;
  for (int jj = 0; jj < 64; jj++){
    int j = jbase + jj;
    if (j >= TCAND) break;
    if (j <= i) continue;
    float4 bj = ((const float4*)obox)[b * TCAND + j];
    float xx1 = fmaxf(bi.x, bj.x), yy1 = fmaxf(bi.y, bj.y);
    float xx2 = fminf(bi.z, bj.z), yy2 = fminf(bi.w, bj.w);
    float iw = fmaxf(__fsub_rn(xx2, xx1), 0.f);
    float ih = fmaxf(__fsub_rn(yy2, yy1), 0.f);
    float inter = __fmul_rn(iw, ih);
    float uni = __fadd_rn(__fsub_rn(__fadd_rn(ai, area[b * TCAND + j]), inter), 1e-9f);
    float iou = inter / uni;
    if (iou > 0.7f) bits |= (1ull << jj);
  }
  supp[((size_t)b * NROWS + i) * NW + w] = bits;
}

// -------- kernel 5: exact greedy scan (1 wave per image, chunked) --------
__global__ __launch_bounds__(64) void nms_scan(const u64* __restrict__ supp,
                                               const int* __restrict__ validarr,
                                               u64* __restrict__ keep_out)
{
  const int b = blockIdx.x;
  const int lane = threadIdx.x;
  u64 rlo = 0ull, rhi = 0ull;   // removed-mask words lane and lane+64
  for (int jj = 0; jj < 64; jj++){
    int i1 = (lane << 6) + jj;
    u64 bad1 = (i1 < TCAND) ? (validarr[b * TCAND + i1] ? 0ull : 1ull) : 1ull;
    rlo |= bad1 << jj;
    int i2 = ((lane + 64) << 6) + jj;
    u64 bad2 = (i2 < TCAND) ? (validarr[b * TCAND + i2] ? 0ull : 1ull) : 1ull;
    rhi |= bad2 << jj;
  }
  for (int c = 0; c < NW; c++){
    u64 rw = (c < 64) ? __shfl(rlo, c) : __shfl(rhi, c - 64);
    u64 diag = supp[((size_t)b * NROWS + (c << 6) + lane) * NW + c];
    // sequential resolve within chunk (rw is uniform across lanes)
    for (int s = 0; s < 64; s++){
      if (!((rw >> s) & 1ull)) rw |= __shfl(diag, s);
    }
    if (c < 64){ if (lane == c) rlo = rw; }
    else       { if (lane == c - 64) rhi = rw; }
    u64 kept = ~rw;
    const u64* rowbase = supp + ((size_t)b * NROWS + (c << 6)) * NW;
    for (int s = 0; s < 64; s++){
      if ((kept >> s) & 1ull){
        rlo |= rowbase[(size_t)s * NW + lane];
        if (lane < 11) rhi |= rowbase[(size_t)s * NW + 64 + lane];
      }
    }
  }
  keep_out[b * 80 + lane] = ~rlo;
  if (lane < 11) keep_out[b * 80 + 64 + lane] = ~rhi;
}

// -------- kernel 6: stable compaction + emit [B,1000,5] --------
__global__ __launch_bounds__(1024) void emit(const u64* __restrict__ keep_out,
                                             const float* __restrict__ s_score,
                                             const float* __restrict__ s_box,
                                             float* __restrict__ out)
{
  const int b = blockIdx.x, t = threadIdx.x;
  __shared__ int part[1024];
  int f[5]; int base = t * 5; int lsum = 0;
  #pragma unroll
  for (int q = 0; q < 5; q++){
    int s = base + q; int kp = 0;
    if (s < TCAND) kp = (int)((keep_out[b * 80 + (s >> 6)] >> (s & 63)) & 1ull);
    f[q] = kp; lsum += kp;
  }
  part[t] = lsum;
  __syncthreads();
  for (int d = 1; d < 1024; d <<= 1){
    int addv = 0;
    if (t >= d) addv = part[t - d];
    __syncthreads();
    part[t] += addv;
    __syncthreads();
  }
  int K = part[1023];
  int kcnt = part[t] - lsum;   // kept before this thread's range
  #pragma unroll
  for (int q = 0; q < 5; q++){
    int s = base + q;
    if (s < TCAND){
      int pos = f[q] ? kcnt : (K + (s - kcnt));
      if (pos < 1000){
        float4 bx = ((const float4*)s_box)[b * TCAND + s];
        float scv = f[q] ? s_score[b * TCAND + s] : NEGV;
        float* o = out + ((size_t)b * 1000 + pos) * 5;
        o[0] = bx.x; o[1] = bx.y; o[2] = bx.z; o[3] = bx.w; o[4] = scv;
      }
      kcnt += f[q];
    }
  }
}

extern "C" void kernel_launch(void* const* d_in, const int* in_sizes, int n_in,
                              void* d_out, int out_size, void* d_ws, size_t ws_size,
                              hipStream_t stream)
{
  (void)in_sizes; (void)n_in; (void)out_size; (void)ws_size;
  const float* feats[5] = {(const float*)d_in[0], (const float*)d_in[1],
                           (const float*)d_in[2], (const float*)d_in[3],
                           (const float*)d_in[4]};
  const float* w_inter  = (const float*)d_in[5];
  const float* b_inter  = (const float*)d_in[6];
  const float* w_logits = (const float*)d_in[7];
  const float* b_logits = (const float*)d_in[8];
  const float* w_reg    = (const float*)d_in[9];
  const float* b_reg    = (const float*)d_in[10];
  const int*   imgp     = (const int*)d_in[11];

  char* ws = (char*)d_ws;
  float* w_r        = (float*)(ws + 0);          // 2,359,296
  float* score_base = (float*)(ws + 2359296);    // 2,095,104
  float* box_base   = (float*)(ws + 4454400);    // 8,380,416
  float* cs         = (float*)(ws + 12834816);   // 38,144
  float* cb         = (float*)(ws + 12872960);   // 152,576
  int*   clvl       = (int*)  (ws + 13025536);   // 38,144
  float* s_score    = (float*)(ws + 13063680);   // 38,144
  float* s_box      = (float*)(ws + 13101824);   // 152,576
  float* obox       = (float*)(ws + 13254400);   // 152,576
  float* area       = (float*)(ws + 13406976);   // 38,144
  int*   validarr   = (int*)  (ws + 13445120);   // 38,144
  u64*   supp       = (u64*)  (ws + 13483264);   // 5,760,000
  u64*   keep_out   = (u64*)  (ws + 19243264);   // 1,280

  hipLaunchKernelGGL(wtrans, dim3((589824 + 255) / 256), dim3(256), 0, stream, w_inter, w_r);

  const int Hs[5] = {256, 128, 64, 32, 16};
  const int STs[5] = {4, 8, 16, 32, 64};
  const int SZs[5] = {32, 64, 128, 256, 512};
  const int FO[5] = {0, 196608, 245760, 258048, 261120};
  for (int l = 0; l < 5; l++){
    int tiles = (Hs[l] / 8) * (Hs[l] / 8);
    hipLaunchKernelGGL(conv_fused, dim3(tiles, 2), dim3(256), 0, stream,
      feats[l], w_r, b_inter, w_logits, b_logits, w_reg, b_reg, imgp,
      score_base, box_base, Hs[l], Hs[l], STs[l], SZs[l], FO[l]);
  }
  hipLaunchKernelGGL(topk_lvl, dim3(5, 2), dim3(1024), 0, stream,
                     score_base, box_base, cs, cb, clvl);
  hipLaunchKernelGGL(gsort, dim3(2), dim3(1024), 0, stream,
                     cs, cb, clvl, imgp, s_score, s_box, obox, area, validarr);
  hipLaunchKernelGGL(iou_mat, dim3((TCAND * NW + 255) / 256, 2), dim3(256), 0, stream,
                     obox, area, supp);
  hipLaunchKernelGGL(nms_scan, dim3(2), dim3(64), 0, stream, supp, validarr, keep_out);
  hipLaunchKernelGGL(emit, dim3(2), dim3(1024), 0, stream, keep_out, s_score, s_box,
                     (float*)d_out);
}

// Round 2
// 5700.672 us; speedup vs baseline: 1.2297x; 1.2297x over previous
//
#include <hip/hip_runtime.h>
#include <cmath>

typedef unsigned int u32;
typedef unsigned long long u64;

#define TCAND 4768
#define RTOT  261888
#define NW    75
#define NROWS 4800
#define NEGV  -1e9f

__device__ __forceinline__ u32 fkey(float s){
  u32 u = __float_as_uint(s);
  return u ^ ((u >> 31) ? 0xFFFFFFFFu : 0x80000000u);
}

// -------- descending bitonic sort of u64 in LDS (N power of two) --------
__device__ void bitonic_desc(u64* a, int N, int t, int nt){
  for (int len = 2; len <= N; len <<= 1){
    for (int inc = len >> 1; inc > 0; inc >>= 1){
      __syncthreads();
      for (int idx = t; idx < (N >> 1); idx += nt){
        int i = 2*idx - (idx & (inc - 1));
        int j = i + inc;
        u64 x = a[i], y = a[j];
        bool descR = ((i & len) == 0);
        bool sw = descR ? (x < y) : (x > y);
        if (sw){ a[i] = y; a[j] = x; }
      }
    }
  }
  __syncthreads();
}

// -------- kernel 0: transpose w_inter [oc][ic*9] -> w_r [ic*9][oc] --------
__global__ void wtrans(const float* __restrict__ w, float* __restrict__ w_r){
  int i = blockIdx.x * 256 + threadIdx.x;
  if (i >= 589824) return;               // 256*2304
  int oc = i / 2304; int r = i - oc * 2304;
  w_r[r * 256 + oc] = w[i];
}

// -------- fused conv3x3 (weights in SGPRs) + heads + decode, all levels --------
// block: 256 thr = 4 waves; wave w owns oc [64w,64w+64); each lane owns 1 px of an
// 8x8 tile, acc[64] = its px across the wave's 64 oc. K-chain order (ic asc, ky, kx)
// and head 16-group+binary-tree reduction replicate the round-1 kernel bit-exactly.
template<int H, int STRIDEV, int ASIZE, int FOFF>
__device__ __forceinline__ void conv_level(
    int rel, const float* __restrict__ feat, const float* __restrict__ w_r,
    const float* __restrict__ b_inter, const float* __restrict__ w_logits,
    const float* __restrict__ b_logits, const float* __restrict__ w_reg,
    const float* __restrict__ b_reg, const int* __restrict__ imgp,
    float* __restrict__ score_base, float* __restrict__ box_base,
    float* lds_x, float* Sbuf)
{
  constexpr int W = H;
  constexpr int TX = H / 8;
  constexpr int TILES = TX * TX;
  const int t = threadIdx.x;
  const int img = rel / TILES;
  const int tile = rel - img * TILES;
  const int x0 = (tile % TX) << 3;
  const int y0 = (tile / TX) << 3;
  const int lane = t & 63;
  const int px_ = lane & 7;
  const int py_ = lane >> 3;
  const int wq = __builtin_amdgcn_readfirstlane(t >> 6);

  float acc[64];
  #pragma unroll
  for (int j = 0; j < 64; j++) acc[j] = 0.f;

  const size_t fb = (size_t)img * 256 * H * W;

  for (int icb = 0; icb < 32; ++icb){
    __syncthreads();
    // stage 8 input planes: 10x10 zero-padded patch each
    for (int k = t; k < 800; k += 256){
      int icl = k / 100; int rem = k - icl * 100; int r = rem / 10; int c = rem - r * 10;
      int gy = y0 + r - 1, gx = x0 + c - 1;
      int ic = (icb << 3) + icl;
      float v = 0.f;
      if (gy >= 0 && gy < H && gx >= 0 && gx < W)
        v = feat[fb + ((size_t)ic * H + gy) * W + gx];
      lds_x[k] = v;
    }
    __syncthreads();
    #pragma unroll 1
    for (int icl = 0; icl < 8; ++icl){
      const int ic = (icb << 3) + icl;
      float xw[9];
      #pragma unroll
      for (int ky = 0; ky < 3; ky++)
        #pragma unroll
        for (int kx = 0; kx < 3; kx++)
          xw[ky * 3 + kx] = lds_x[icl * 100 + (py_ + ky) * 10 + (px_ + kx)];
      #pragma unroll
      for (int tap = 0; tap < 9; tap++){
        const float* __restrict__ wt = w_r + (ic * 9 + tap) * 256 + wq * 64;
        const float xv = xw[tap];
        #pragma unroll
        for (int j = 0; j < 64; j++)
          acc[j] = __builtin_fmaf(wt[j], xv, acc[j]);
      }
    }
  }
  // bias + relu (in place)
  #pragma unroll
  for (int j = 0; j < 64; j++) acc[j] = fmaxf(acc[j] + b_inter[wq * 64 + j], 0.f);

  // head partials: per output o, 4 local groups of 16 consecutive oc, sequential
  // o16 chain, then in-wave tree (p0+p1)+(p2+p3)  [= butterfly m=1,2]
  #pragma unroll
  for (int o = 0; o < 15; o++){
    const float* __restrict__ wh = (o < 3) ? (w_logits + o * 256) : (w_reg + (o - 3) * 256);
    float p0 = 0.f, p1 = 0.f, p2 = 0.f, p3 = 0.f;
    #pragma unroll
    for (int o16 = 0; o16 < 16; o16++){
      p0 = __builtin_fmaf(wh[wq * 64 +  0 + o16], acc[ 0 + o16], p0);
      p1 = __builtin_fmaf(wh[wq * 64 + 16 + o16], acc[16 + o16], p1);
      p2 = __builtin_fmaf(wh[wq * 64 + 32 + o16], acc[32 + o16], p2);
      p3 = __builtin_fmaf(wh[wq * 64 + 48 + o16], acc[48 + o16], p3);
    }
    float sv = (p0 + p1) + (p2 + p3);
    Sbuf[(wq * 15 + o) * 64 + lane] = sv;
  }
  __syncthreads();

  // cross-wave tree (S0+S1)+(S2+S3)  [= butterfly m=4,8] + decode (verbatim round-1)
  if (t < 192){
    int a = t >> 6; int px = t & 63;
    int r = px >> 3, c = px & 7;
    int y = y0 + r, x = x0 + c;
    float img_f = (float)(*imgp);
    #define FIN(o) (((Sbuf[(0*15+(o))*64+px] + Sbuf[(1*15+(o))*64+px]) + \
                     (Sbuf[(2*15+(o))*64+px] + Sbuf[(3*15+(o))*64+px])))
    float sc = FIN(a) + b_logits[a];
    float d0 = FIN(3 + a * 4 + 0) + b_reg[a * 4 + 0];
    float d1 = FIN(3 + a * 4 + 1) + b_reg[a * 4 + 1];
    float d2 = FIN(3 + a * 4 + 2) + b_reg[a * 4 + 2];
    float d3 = FIN(3 + a * 4 + 3) + b_reg[a * 4 + 3];
    #undef FIN
    double ar = (a == 0) ? 0.5 : ((a == 1) ? 1.0 : 2.0);
    double area_d = (double)ASIZE * (double)ASIZE;
    double wd = sqrt(area_d / ar);
    double hd = ar * wd;
    float bx1 = (float)(-wd * 0.5), by1 = (float)(-hd * 0.5);
    float bx2 = (float)( wd * 0.5), by2 = (float)( hd * 0.5);
    float sx = (float)(x * STRIDEV), sy = (float)(y * STRIDEV);
    float ax1 = sx + bx1, ay1 = sy + by1, ax2 = sx + bx2, ay2 = sy + by2;
    float aw = __fsub_rn(ax2, ax1), ah = __fsub_rn(ay2, ay1);
    float acx = __fadd_rn(ax1, __fmul_rn(0.5f, aw));
    float acy = __fadd_rn(ay1, __fmul_rn(0.5f, ah));
    const float CLAMP = (float)4.135166556742356;
    float dwv = fminf(d2, CLAMP), dhv = fminf(d3, CLAMP);
    float pcx = __fadd_rn(__fmul_rn(d0, aw), acx);
    float pcy = __fadd_rn(__fmul_rn(d1, ah), acy);
    float pw = __fmul_rn((float)exp((double)dwv), aw);
    float ph = __fmul_rn((float)exp((double)dhv), ah);
    float hx = __fmul_rn(0.5f, pw), hy = __fmul_rn(0.5f, ph);
    float X1 = __fsub_rn(pcx, hx), Y1 = __fsub_rn(pcy, hy);
    float X2 = __fadd_rn(pcx, hx), Y2 = __fadd_rn(pcy, hy);
    X1 = fminf(fmaxf(X1, 0.f), img_f); Y1 = fminf(fmaxf(Y1, 0.f), img_f);
    X2 = fminf(fmaxf(X2, 0.f), img_f); Y2 = fminf(fmaxf(Y2, 0.f), img_f);
    int gi = (y * W + x) * 3 + a;
    size_t oidx = (size_t)img * RTOT + FOFF + gi;
    score_base[oidx] = sc;
    ((float4*)box_base)[oidx] = make_float4(X1, Y1, X2, Y2);
  }
}

__global__ __launch_bounds__(256, 4) void conv_all(
    const float* __restrict__ f2, const float* __restrict__ f3,
    const float* __restrict__ f4, const float* __restrict__ f5,
    const float* __restrict__ f6, const float* __restrict__ w_r,
    const float* __restrict__ b_inter, const float* __restrict__ w_logits,
    const float* __restrict__ b_logits, const float* __restrict__ w_reg,
    const float* __restrict__ b_reg, const int* __restrict__ imgp,
    float* __restrict__ score_base, float* __restrict__ box_base)
{
  __shared__ float lds_x[800];
  __shared__ float Sbuf[3840];
  const int bid = blockIdx.x;
  if (bid < 2048)
    conv_level<256, 4, 32, 0>(bid, f2, w_r, b_inter, w_logits, b_logits, w_reg, b_reg,
                              imgp, score_base, box_base, lds_x, Sbuf);
  else if (bid < 2560)
    conv_level<128, 8, 64, 196608>(bid - 2048, f3, w_r, b_inter, w_logits, b_logits, w_reg,
                                   b_reg, imgp, score_base, box_base, lds_x, Sbuf);
  else if (bid < 2688)
    conv_level<64, 16, 128, 245760>(bid - 2560, f4, w_r, b_inter, w_logits, b_logits, w_reg,
                                    b_reg, imgp, score_base, box_base, lds_x, Sbuf);
  else if (bid < 2720)
    conv_level<32, 32, 256, 258048>(bid - 2688, f5, w_r, b_inter, w_logits, b_logits, w_reg,
                                    b_reg, imgp, score_base, box_base, lds_x, Sbuf);
  else
    conv_level<16, 64, 512, 261120>(bid - 2720, f6, w_r, b_inter, w_logits, b_logits, w_reg,
                                    b_reg, imgp, score_base, box_base, lds_x, Sbuf);
}

// -------- kernel 2: per (level,image) exact top-k (radix select + bitonic) --------
__global__ __launch_bounds__(1024) void topk_lvl(
    const float* __restrict__ score_base, const float* __restrict__ box_base,
    float* __restrict__ cs, float* __restrict__ cb, int* __restrict__ clvl)
{
  const int lvl = blockIdx.x, b = blockIdx.y;
  const int Rtab[5] = {196608, 49152, 12288, 3072, 768};
  const int Ktab[5] = {1000, 1000, 1000, 1000, 768};
  const int Ftab[5] = {0, 196608, 245760, 258048, 261120};
  const int Ctab[5] = {0, 1000, 2000, 3000, 4000};
  const int R = Rtab[lvl], kk = Ktab[lvl], foff = Ftab[lvl], coff = Ctab[lvl];
  const float* sc = score_base + (size_t)b * RTOT + foff;
  const int t = threadIdx.x;
  __shared__ u32 hist[256];
  __shared__ u32 sh_prefix, sh_r;
  __shared__ u32 cgt, ceq;
  __shared__ u64 sel[1024];
  __shared__ u64 eqb[1024];
  if (t == 0){ sh_prefix = 0u; sh_r = (u32)kk; }
  __syncthreads();
  for (int pass = 0; pass < 4; ++pass){
    if (t < 256) hist[t] = 0u;
    __syncthreads();
    u32 prefix = sh_prefix;
    int shift = 24 - 8 * pass;
    u32 maskHi = (pass == 0) ? 0u : (0xFFFFFFFFu << (shift + 8));
    for (int i = t; i < R; i += 1024){
      u32 key = fkey(sc[i]);
      if ((key & maskHi) == prefix) atomicAdd(&hist[(key >> shift) & 255u], 1u);
    }
    __syncthreads();
    if (t == 0){
      u32 r = sh_r; u32 run = 0; int chosen = 255;
      for (int bv = 255; bv >= 0; --bv){
        u32 c = hist[bv];
        if (run + c >= r){ chosen = bv; break; }
        run += c;
      }
      sh_prefix = prefix | ((u32)chosen << shift);
      sh_r = r - run;
    }
    __syncthreads();
  }
  const u32 Tkey = sh_prefix; const u32 need_eq = sh_r;
  if (t == 0){ cgt = 0u; ceq = 0u; }
  __syncthreads();
  for (int i = t; i < R; i += 1024){
    u32 key = fkey(sc[i]);
    if (key > Tkey){
      u32 p = atomicAdd(&cgt, 1u);
      sel[p] = (((u64)key) << 32) | (u64)(0xFFFFFFFFu - (u32)i);
    } else if (key == Tkey){
      u32 e = atomicAdd(&ceq, 1u);
      if (e < 1024u) eqb[e] = (u64)(0xFFFFFFFFu - (u32)i);
    }
  }
  __syncthreads();
  u32 nGt = cgt; u32 nEq = ceq > 1024u ? 1024u : ceq;
  if ((u32)t >= nEq) eqb[t] = 0ull;
  __syncthreads();
  bitonic_desc(eqb, 1024, t, 1024);
  if ((u32)t < need_eq) sel[nGt + t] = (((u64)Tkey) << 32) | (eqb[t] & 0xFFFFFFFFull);
  if (t >= kk) sel[t] = 0ull;
  __syncthreads();
  bitonic_desc(sel, 1024, t, 1024);
  if (t < kk){
    u64 v = sel[t];
    u32 i = 0xFFFFFFFFu - (u32)(v & 0xFFFFFFFFull);
    int dst = b * TCAND + coff + t;
    cs[dst] = sc[i];
    ((float4*)cb)[dst] = ((const float4*)box_base)[(size_t)b * RTOT + foff + i];
    clvl[dst] = lvl;
  }
}

// -------- kernel 3: per-image global stable sort + NMS prep --------
__global__ __launch_bounds__(1024) void gsort(
    const float* __restrict__ cs, const float* __restrict__ cb, const int* __restrict__ clvl,
    const int* __restrict__ imgp,
    float* __restrict__ s_score, float* __restrict__ s_box, float* __restrict__ obox,
    float* __restrict__ area, int* __restrict__ validarr)
{
  const int b = blockIdx.x, t = threadIdx.x;
  __shared__ u64 arr[8192];
  for (int i = t; i < 8192; i += 1024){
    u64 v = 0ull;
    if (i < TCAND){
      u32 key = fkey(cs[b * TCAND + i]);
      v = (((u64)key) << 32) | (u64)(0xFFFFFFFFu - (u32)i);
    }
    arr[i] = v;
  }
  __syncthreads();
  bitonic_desc(arr, 8192, t, 1024);
  const float img = (float)(*imgp);
  const float off1 = img + 1.0f;
  for (int s = t; s < TCAND; s += 1024){
    u32 ci = 0xFFFFFFFFu - (u32)(arr[s] & 0xFFFFFFFFull);
    int src = b * TCAND + (int)ci;
    int dst = b * TCAND + s;
    float scv = cs[src];
    float4 bx = ((const float4*)cb)[src];
    s_score[dst] = scv;
    ((float4*)s_box)[dst] = bx;
    float lv = (float)clvl[src];
    float tt = __fmul_rn(lv, off1);
    float o0 = __fadd_rn(bx.x, tt), o1 = __fadd_rn(bx.y, tt);
    float o2 = __fadd_rn(bx.z, tt), o3 = __fadd_rn(bx.w, tt);
    ((float4*)obox)[dst] = make_float4(o0, o1, o2, o3);
    area[dst] = __fmul_rn(__fsub_rn(o2, o0), __fsub_rn(o3, o1));
    validarr[dst] = (bx.z > bx.x && bx.w > bx.y) ? 1 : 0;
  }
}

// -------- kernel 4: suppression bit-matrix (j>i, IoU>0.7) --------
__global__ void iou_mat(const float* __restrict__ obox, const float* __restrict__ area,
                        u64* __restrict__ supp)
{
  const int b = blockIdx.y;
  int wid = blockIdx.x * 256 + threadIdx.x;
  const int total = TCAND * NW;
  if (wid >= total) return;
  int i = wid / NW, w = wid - i * NW;
  float4 bi = ((const float4*)obox)[b * TCAND + i];
  float ai = area[b * TCAND + i];
  u64 bits = 0ull;
  int jbase = w << 6;
  for (int jj = 0; jj < 64; jj++){
    int j = jbase + jj;
    if (j >= TCAND) break;
    if (j <= i) continue;
    float4 bj = ((const float4*)obox)[b * TCAND + j];
    float xx1 = fmaxf(bi.x, bj.x), yy1 = fmaxf(bi.y, bj.y);
    float xx2 = fminf(bi.z, bj.z), yy2 = fminf(bi.w, bj.w);
    float iw = fmaxf(__fsub_rn(xx2, xx1), 0.f);
    float ih = fmaxf(__fsub_rn(yy2, yy1), 0.f);
    float inter = __fmul_rn(iw, ih);
    float uni = __fadd_rn(__fsub_rn(__fadd_rn(ai, area[b * TCAND + j]), inter), 1e-9f);
    float iou = inter / uni;
    if (iou > 0.7f) bits |= (1ull << jj);
  }
  supp[((size_t)b * NROWS + i) * NW + w] = bits;
}

// -------- kernel 5: exact greedy scan (1 wave per image, chunked) --------
__global__ __launch_bounds__(64) void nms_scan(const u64* __restrict__ supp,
                                               const int* __restrict__ validarr,
                                               u64* __restrict__ keep_out)
{
  const int b = blockIdx.x;
  const int lane = threadIdx.x;
  u64 rlo = 0ull, rhi = 0ull;
  for (int jj = 0; jj < 64; jj++){
    int i1 = (lane << 6) + jj;
    u64 bad1 = (i1 < TCAND) ? (validarr[b * TCAND + i1] ? 0ull : 1ull) : 1ull;
    rlo |= bad1 << jj;
    int i2 = ((lane + 64) << 6) + jj;
    u64 bad2 = (i2 < TCAND) ? (validarr[b * TCAND + i2] ? 0ull : 1ull) : 1ull;
    rhi |= bad2 << jj;
  }
  for (int c = 0; c < NW; c++){
    u64 rw = (c < 64) ? __shfl(rlo, c) : __shfl(rhi, c - 64);
    u64 diag = supp[((size_t)b * NROWS + (c << 6) + lane) * NW + c];
    for (int s = 0; s < 64; s++){
      if (!((rw >> s) & 1ull)) rw |= __shfl(diag, s);
    }
    if (c < 64){ if (lane == c) rlo = rw; }
    else       { if (lane == c - 64) rhi = rw; }
    u64 kept = ~rw;
    const u64* rowbase = supp + ((size_t)b * NROWS + (c << 6)) * NW;
    for (int s = 0; s < 64; s++){
      if ((kept >> s) & 1ull){
        rlo |= rowbase[(size_t)s * NW + lane];
        if (lane < 11) rhi |= rowbase[(size_t)s * NW + 64 + lane];
      }
    }
  }
  keep_out[b * 80 + lane] = ~rlo;
  if (lane < 11) keep_out[b * 80 + 64 + lane] = ~rhi;
}

// -------- kernel 6: stable compaction + emit [B,1000,5] --------
__global__ __launch_bounds__(1024) void emit(const u64* __restrict__ keep_out,
                                             const float* __restrict__ s_score,
                                             const float* __restrict__ s_box,
                                             float* __restrict__ out)
{
  const int b = blockIdx.x, t = threadIdx.x;
  __shared__ int part[1024];
  int f[5]; int base = t * 5; int lsum = 0;
  #pragma unroll
  for (int q = 0; q < 5; q++){
    int s = base + q; int kp = 0;
    if (s < TCAND) kp = (int)((keep_out[b * 80 + (s >> 6)] >> (s & 63)) & 1ull);
    f[q] = kp; lsum += kp;
  }
  part[t] = lsum;
  __syncthreads();
  for (int d = 1; d < 1024; d <<= 1){
    int addv = 0;
    if (t >= d) addv = part[t - d];
    __syncthreads();
    part[t] += addv;
    __syncthreads();
  }
  int K = part[1023];
  int kcnt = part[t] - lsum;
  #pragma unroll
  for (int q = 0; q < 5; q++){
    int s = base + q;
    if (s < TCAND){
      int pos = f[q] ? kcnt : (K + (s - kcnt));
      if (pos < 1000){
        float4 bx = ((const float4*)s_box)[b * TCAND + s];
        float scv = f[q] ? s_score[b * TCAND + s] : NEGV;
        float* o = out + ((size_t)b * 1000 + pos) * 5;
        o[0] = bx.x; o[1] = bx.y; o[2] = bx.z; o[3] = bx.w; o[4] = scv;
      }
      kcnt += f[q];
    }
  }
}

extern "C" void kernel_launch(void* const* d_in, const int* in_sizes, int n_in,
                              void* d_out, int out_size, void* d_ws, size_t ws_size,
                              hipStream_t stream)
{
  (void)in_sizes; (void)n_in; (void)out_size; (void)ws_size;
  const float* f2 = (const float*)d_in[0];
  const float* f3 = (const float*)d_in[1];
  const float* f4 = (const float*)d_in[2];
  const float* f5 = (const float*)d_in[3];
  const float* f6 = (const float*)d_in[4];
  const float* w_inter  = (const float*)d_in[5];
  const float* b_inter  = (const float*)d_in[6];
  const float* w_logits = (const float*)d_in[7];
  const float* b_logits = (const float*)d_in[8];
  const float* w_reg    = (const float*)d_in[9];
  const float* b_reg    = (const float*)d_in[10];
  const int*   imgp     = (const int*)d_in[11];

  char* ws = (char*)d_ws;
  float* w_r        = (float*)(ws + 0);          // 2,359,296
  float* score_base = (float*)(ws + 2359296);    // 2,095,104
  float* box_base   = (float*)(ws + 4454400);    // 8,380,416
  float* cs         = (float*)(ws + 12834816);   // 38,144
  float* cb         = (float*)(ws + 12872960);   // 152,576
  int*   clvl       = (int*)  (ws + 13025536);   // 38,144
  float* s_score    = (float*)(ws + 13063680);   // 38,144
  float* s_box      = (float*)(ws + 13101824);   // 152,576
  float* obox       = (float*)(ws + 13254400);   // 152,576
  float* area       = (float*)(ws + 13406976);   // 38,144
  int*   validarr   = (int*)  (ws + 13445120);   // 38,144
  u64*   supp       = (u64*)  (ws + 13483264);   // 5,760,000
  u64*   keep_out   = (u64*)  (ws + 19243264);   // 1,280

  hipLaunchKernelGGL(wtrans, dim3((589824 + 255) / 256), dim3(256), 0, stream, w_inter, w_r);

  hipLaunchKernelGGL(conv_all, dim3(2728), dim3(256), 0, stream,
                     f2, f3, f4, f5, f6, w_r, b_inter, w_logits, b_logits, w_reg, b_reg,
                     imgp, score_base, box_base);

  hipLaunchKernelGGL(topk_lvl, dim3(5, 2), dim3(1024), 0, stream,
                     score_base, box_base, cs, cb, clvl);
  hipLaunchKernelGGL(gsort, dim3(2), dim3(1024), 0, stream,
                     cs, cb, clvl, imgp, s_score, s_box, obox, area, validarr);
  hipLaunchKernelGGL(iou_mat, dim3((TCAND * NW + 255) / 256, 2), dim3(256), 0, stream,
                     obox, area, supp);
  hipLaunchKernelGGL(nms_scan, dim3(2), dim3(64), 0, stream, supp, validarr, keep_out);
  hipLaunchKernelGGL(emit, dim3(2), dim3(1024), 0, stream, keep_out, s_score, s_box,
                     (float*)d_out);
}